// Round 8
// baseline (485.100 us; speedup 1.0000x reference)
//
#include <hip/hip_runtime.h>

#define N_NODES 50000
#define N_EDGES 1600000
#define CAP 64            // bucket capacity per node; Poisson(32) tail @64 ~ 1e-7
#define OVF_CAP 8192

// Workspace element offsets (4-byte units). Peak ~77.4 MB.
#define O_CNTO   0         // int[50000]  out-degree
#define O_CNTI   50000     // int[50000]  in-degree (also bucket fill)
#define O_OVFN   100000    // int[1]      overflow count
#define O_OVF    100002    // int2[8192]  overflow (dst,src) pairs
#define O_BUCKET 120000    // int[50000*64] src per slot
#define O_HB     3320000   // uint[3.2M]  bf16x2 h*norm_out
#define O_AGGB   6520000   // uint[3.2M]  bf16x2 agg rows (256 B/node)
#define O_WT     9720000   // uint[24576] bf16 W^T for Q,K,V: [3][128 n][64 k-pairs]
#define O_QB     9750000   // uint[3.2M]  bf16x2 Q rows (64 uints/node)
#define O_KB     12950000  // uint[3.2M]  bf16x2 K rows
#define O_VB     16150000  // uint[3.2M]  bf16x2 V rows

typedef unsigned int uint;
typedef __attribute__((ext_vector_type(8))) short short8;
typedef __attribute__((ext_vector_type(4))) float floatx4;

union U16 { uint4 u; short8 s; };

__device__ __forceinline__ uint f2bf2(float a, float b) {
    uint ua = __float_as_uint(a); ua = (ua + 0x7fffu + ((ua >> 16) & 1u)) >> 16;
    uint ub = __float_as_uint(b); ub = (ub + 0x7fffu + ((ub >> 16) & 1u)) >> 16;
    return ua | (ub << 16);
}
__device__ __forceinline__ float bflo(uint u) { return __uint_as_float(u << 16); }
__device__ __forceinline__ float bfhi(uint u) { return __uint_as_float(u & 0xffff0000u); }

// One-pass build: out-degree histogram + dst-buckets (with overflow safety net).
__global__ __launch_bounds__(256) void k_build(const int* __restrict__ src,
                                               const int* __restrict__ dst,
                                               int* cnt_out, int* cnt_in,
                                               int* __restrict__ bucket,
                                               int* ovf_n, int2* __restrict__ ovf) {
    int e = blockIdx.x * 256 + threadIdx.x;
    if (e < N_EDGES) {
        int s = src[e], d = dst[e];
        atomicAdd(&cnt_out[s], 1);
        int pos = atomicAdd(&cnt_in[d], 1);
        if (pos < CAP) {
            bucket[(d << 6) + pos] = s;
        } else {
            int o = atomicAdd(ovf_n, 1);
            if (o < OVF_CAP) ovf[o] = make_int2(d, s);
        }
    }
}

// W^T cast: wt[y][n][k2] = bf16x2(W_y[2k2][n], W_y[2k2+1][n])
__global__ __launch_bounds__(256) void k_wt(const float* __restrict__ WQ,
                                            const float* __restrict__ WK,
                                            const float* __restrict__ WV,
                                            uint* __restrict__ wt) {
    int idx = blockIdx.x * 256 + threadIdx.x;   // [0, 3*8192)
    if (idx < 3 * 8192) {
        int y = idx >> 13;
        int rem = idx & 8191;
        int k2 = rem >> 7;          // 0..63
        int n  = rem & 127;         // coalesced reads
        const float* W = (y == 0) ? WQ : (y == 1) ? WK : WV;
        float a = W[(2 * k2) * 128 + n];
        float b = W[(2 * k2 + 1) * 128 + n];
        wt[(y << 13) + (n << 6) + k2] = f2bf2(a, b);
    }
}

// hb[n][j] = bf16(h[n][j] * rsqrt(max(deg_out,1)))
__global__ __launch_bounds__(256) void k_hb(const float* __restrict__ h,
                                            const int* __restrict__ cnt_out,
                                            uint* __restrict__ hb) {
    int idx = blockIdx.x * 256 + threadIdx.x;   // [0, N*64)
    if (idx < N_NODES * 64) {
        int n = idx >> 6;
        float no = rsqrtf(fmaxf((float)cnt_out[n], 1.0f));
        float2 hv = *(const float2*)(h + ((size_t)idx << 1));
        hb[idx] = f2bf2(hv.x * no, hv.y * no);
    }
}

// aggb[n] = bf16( rsqrt(max(deg_in,1)) * sum_{slots of n} hb[s] )
__global__ __launch_bounds__(256) void k_agg(
    const int* __restrict__ cnt_in, const int* __restrict__ bucket,
    const int* __restrict__ ovf_n, const int2* __restrict__ ovf,
    const uint* __restrict__ hb, uint* __restrict__ aggb)
{
    int n = blockIdx.x * 4 + (threadIdx.x >> 6);
    int lane = threadIdx.x & 63;
    int cnt = cnt_in[n];
    int m = min(cnt, CAP);
    const int* b = bucket + ((size_t)n << 6);
    float ax = 0.f, ay = 0.f;
    int i = 0;
    for (; i + 4 <= m; i += 4) {
        int s0 = b[i], s1 = b[i + 1], s2 = b[i + 2], s3 = b[i + 3];
        uint u0 = hb[((size_t)s0 << 6) + lane];
        uint u1 = hb[((size_t)s1 << 6) + lane];
        uint u2 = hb[((size_t)s2 << 6) + lane];
        uint u3 = hb[((size_t)s3 << 6) + lane];
        ax += bflo(u0) + bflo(u1) + bflo(u2) + bflo(u3);
        ay += bfhi(u0) + bfhi(u1) + bfhi(u2) + bfhi(u3);
    }
    for (; i < m; ++i) {
        int s = b[i];
        uint u = hb[((size_t)s << 6) + lane];
        ax += bflo(u);
        ay += bfhi(u);
    }
    if (cnt > CAP) {                       // statistically never; correctness net
        int on = min(*ovf_n, OVF_CAP);
        for (int j = 0; j < on; ++j) {
            int2 p = ovf[j];
            if (p.x == n) {
                uint u = hb[((size_t)p.y << 6) + lane];
                ax += bflo(u);
                ay += bfhi(u);
            }
        }
    }
    float ni = rsqrtf(fmaxf((float)cnt, 1.0f));
    aggb[((size_t)n << 6) + lane] = f2bf2(ax * ni, ay * ni);
}

// Fused QKV projection via bf16 MFMA. grid (391, 3): y=0 Q, y=1 K, y=2 V,
// all written as bf16 pair-packed rows (64 uints/node).
__global__ __launch_bounds__(256) void k_qkv(
    const uint* __restrict__ aggb, const uint* __restrict__ wt,
    const float* __restrict__ bQ, const float* __restrict__ bK,
    const float* __restrict__ bV,
    uint* __restrict__ qb, uint* __restrict__ kb, uint* __restrict__ vb)
{
    const int y = blockIdx.y;
    const int row0 = blockIdx.x * 128;
    const float* bias = (y == 0) ? bQ : (y == 1) ? bK : bV;
    uint* obuf = (y == 0) ? qb : (y == 1) ? kb : vb;

    __shared__ uint sA[128 * 68];   // A tile, row stride 68 uints

    const int t = threadIdx.x;
    for (int idx = t; idx < 128 * 16; idx += 256) {
        int r = idx >> 4, c4 = (idx & 15) << 2;
        int row = row0 + r;
        uint4 v = make_uint4(0u, 0u, 0u, 0u);
        if (row < N_NODES) v = *(const uint4*)(aggb + ((size_t)row << 6) + c4);
        *(uint4*)(&sA[r * 68 + c4]) = v;
    }
    __syncthreads();

    const int wave = t >> 6;
    const int lane = t & 63;
    const int mrow = lane & 15;     // m (A) / n (B) / col (C)
    const int kq   = lane >> 4;     // 0..3
    const int mbase = wave * 32;
    const uint* wty = wt + (y << 13);

    floatx4 acc[2][8];
    for (int a = 0; a < 2; ++a)
        for (int b = 0; b < 8; ++b)
            acc[a][b] = (floatx4){0.f, 0.f, 0.f, 0.f};

    for (int kc = 0; kc < 128; kc += 32) {
        int koff = (kc >> 1) + (kq << 2);    // uint offset within a row
        short8 afr[2], bfr[8];
        for (int mt = 0; mt < 2; ++mt) {
            U16 u; u.u = *(const uint4*)(&sA[(mbase + mt * 16 + mrow) * 68 + koff]);
            afr[mt] = u.s;
        }
        for (int nt = 0; nt < 8; ++nt) {
            U16 u; u.u = *(const uint4*)(wty + ((nt * 16 + mrow) << 6) + koff);
            bfr[nt] = u.s;
        }
        for (int mt = 0; mt < 2; ++mt)
            for (int nt = 0; nt < 8; ++nt)
                acc[mt][nt] = __builtin_amdgcn_mfma_f32_16x16x32_bf16(
                    afr[mt], bfr[nt], acc[mt][nt], 0, 0, 0);
    }

    // C/D: col = lane&15 (= mrow), row = kq*4 + reg. Pack pairs via shfl_xor(1).
    for (int mt = 0; mt < 2; ++mt) {
        int rbase = row0 + mbase + mt * 16 + kq * 4;
        for (int nt = 0; nt < 8; ++nt) {
            int c = nt * 16 + mrow;
            float bv = bias[c];
            for (int r = 0; r < 4; ++r) {
                float v = fmaxf(acc[mt][nt][r] + bv, 0.f);
                float pv = __shfl_xor(v, 1);
                int row = rbase + r;
                if (((lane & 1) == 0) && row < N_NODES)
                    obuf[((size_t)row << 6) + (c >> 1)] = f2bf2(v, pv);
            }
        }
    }
}

// Attention gather, head-per-lane: wave = 8 heads (lane>>3) x 8 edge slots (lane&7).
// Each lane computes a full 16-dim head dot in-registers; 1 exp per (edge,head).
__global__ __launch_bounds__(256) void k_attn(
    const int* __restrict__ cnt_in, const int* __restrict__ bucket,
    const int* __restrict__ ovf_n, const int2* __restrict__ ovf,
    const uint* __restrict__ qb, const uint* __restrict__ kb,
    const uint* __restrict__ vb, float* __restrict__ out)
{
    int n = blockIdx.x * 4 + (threadIdx.x >> 6);
    int lane = threadIdx.x & 63;
    int hh = lane >> 3;     // head
    int g  = lane & 7;      // edge slot
    int cnt = cnt_in[n];
    int m = min(cnt, CAP);
    const int* b = bucket + ((size_t)n << 6);
    int sb = (lane < m) ? b[lane] : 0;       // preload bucket row

    // Q head slice -> 16 floats
    float qf[16];
    {
        const uint* qp = qb + ((size_t)n << 6) + (hh << 3);
        uint4 a = *(const uint4*)qp;
        uint4 c = *(const uint4*)(qp + 4);
        uint uu[8] = {a.x, a.y, a.z, a.w, c.x, c.y, c.z, c.w};
        #pragma unroll
        for (int j = 0; j < 8; ++j) { qf[2*j] = bflo(uu[j]); qf[2*j+1] = bfhi(uu[j]); }
    }

    float vacc[16];
    #pragma unroll
    for (int j = 0; j < 16; ++j) vacc[j] = 0.f;
    float zacc = 0.f;

    for (int i = 0; i < m; i += 8) {
        int e = i + g;
        int s = __shfl(sb, e);              // wraps mod 64; gated by valid
        bool valid = e < m;
        if (valid) {
            const uint* kp = kb + ((size_t)s << 6) + (hh << 3);
            uint4 ka = *(const uint4*)kp;
            uint4 kc = *(const uint4*)(kp + 4);
            uint ku[8] = {ka.x, ka.y, ka.z, ka.w, kc.x, kc.y, kc.z, kc.w};
            float p = 0.f;
            #pragma unroll
            for (int j = 0; j < 8; ++j)
                p += bflo(ku[j]) * qf[2*j] + bfhi(ku[j]) * qf[2*j+1];
            float sc = __expf(fminf(fmaxf(p * 0.25f, -10.f), 10.f));
            const uint* vp = vb + ((size_t)s << 6) + (hh << 3);
            uint4 va = *(const uint4*)vp;
            uint4 vc = *(const uint4*)(vp + 4);
            uint vu[8] = {va.x, va.y, va.z, va.w, vc.x, vc.y, vc.z, vc.w};
            #pragma unroll
            for (int j = 0; j < 8; ++j) {
                vacc[2*j]   += sc * bflo(vu[j]);
                vacc[2*j+1] += sc * bfhi(vu[j]);
            }
            zacc += sc;
        }
    }

    if (cnt > CAP) {                       // statistically never; correctness net
        int on = min(*ovf_n, OVF_CAP);
        for (int j2 = 0; j2 < on; ++j2) {
            int2 pr = ovf[j2];
            if (pr.x == n && g == 0) {
                int s = pr.y;
                const uint* kp = kb + ((size_t)s << 6) + (hh << 3);
                uint4 ka = *(const uint4*)kp;
                uint4 kc = *(const uint4*)(kp + 4);
                uint ku[8] = {ka.x, ka.y, ka.z, ka.w, kc.x, kc.y, kc.z, kc.w};
                float p = 0.f;
                for (int j = 0; j < 8; ++j)
                    p += bflo(ku[j]) * qf[2*j] + bfhi(ku[j]) * qf[2*j+1];
                float sc = __expf(fminf(fmaxf(p * 0.25f, -10.f), 10.f));
                const uint* vp = vb + ((size_t)s << 6) + (hh << 3);
                uint4 va = *(const uint4*)vp;
                uint4 vc = *(const uint4*)(vp + 4);
                uint vu[8] = {va.x, va.y, va.z, va.w, vc.x, vc.y, vc.z, vc.w};
                for (int j = 0; j < 8; ++j) {
                    vacc[2*j]   += sc * bflo(vu[j]);
                    vacc[2*j+1] += sc * bfhi(vu[j]);
                }
                zacc += sc;
            }
        }
    }

    // reduce across the 8 edge slots (consecutive lanes within a head group)
    #pragma unroll
    for (int mask = 1; mask <= 4; mask <<= 1) {
        #pragma unroll
        for (int j = 0; j < 16; ++j) vacc[j] += __shfl_xor(vacc[j], mask);
        zacc += __shfl_xor(zacc, mask);
    }

    float inv = 1.0f / (zacc + 1e-6f);
    float2 o; o.x = vacc[2*g] * inv; o.y = vacc[2*g+1] * inv;
    *(float2*)(out + ((size_t)n << 7) + (hh << 4) + (g << 1)) = o;
}

extern "C" void kernel_launch(void* const* d_in, const int* in_sizes, int n_in,
                              void* d_out, int out_size, void* d_ws, size_t ws_size,
                              hipStream_t stream) {
    const float* h   = (const float*)d_in[0];
    const float* WQ  = (const float*)d_in[1];
    const float* bQ  = (const float*)d_in[2];
    const float* WK  = (const float*)d_in[3];
    const float* bK  = (const float*)d_in[4];
    const float* WV  = (const float*)d_in[5];
    const float* bV  = (const float*)d_in[6];
    const int*   src = (const int*)d_in[7];
    const int*   dst = (const int*)d_in[8];
    float* out = (float*)d_out;
    float* ws  = (float*)d_ws;
    int*   wsi = (int*)d_ws;

    int*   cnt_out = wsi + O_CNTO;
    int*   cnt_in  = wsi + O_CNTI;
    int*   ovf_n   = wsi + O_OVFN;
    int2*  ovf     = (int2*)(wsi + O_OVF);
    int*   bucket  = wsi + O_BUCKET;
    uint*  hb      = (uint*)(ws + O_HB);
    uint*  aggb    = (uint*)(ws + O_AGGB);
    uint*  wt      = (uint*)(ws + O_WT);
    uint*  qb      = (uint*)(ws + O_QB);
    uint*  kb      = (uint*)(ws + O_KB);
    uint*  vb      = (uint*)(ws + O_VB);

    hipMemsetAsync(wsi, 0, (2 * N_NODES + 2) * sizeof(int), stream);

    k_wt<<<(3 * 8192 + 255) / 256, 256, 0, stream>>>(WQ, WK, WV, wt);
    k_build<<<N_EDGES / 256, 256, 0, stream>>>(src, dst, cnt_out, cnt_in,
                                               bucket, ovf_n, ovf);
    k_hb<<<(N_NODES * 64 + 255) / 256, 256, 0, stream>>>(h, cnt_out, hb);

    k_agg<<<N_NODES / 4, 256, 0, stream>>>(cnt_in, bucket, ovf_n, ovf, hb, aggb);

    dim3 g_qkv((N_NODES + 127) / 128, 3);
    k_qkv<<<g_qkv, 256, 0, stream>>>(aggb, wt, bQ, bK, bV, qb, kb, vb);

    k_attn<<<N_NODES / 4, 256, 0, stream>>>(cnt_in, bucket, ovf_n, ovf,
                                            qb, kb, vb, out);
}

// Round 9
// 468.980 us; speedup vs baseline: 1.0344x; 1.0344x over previous
//
#include <hip/hip_runtime.h>

#define N_NODES 50000
#define N_EDGES 1600000
#define CAP 64            // bucket capacity per node; Poisson(32) tail @64 ~ 1e-7
#define OVF_CAP 8192

// Workspace element offsets (4-byte units). Peak ~77.4 MB.
#define O_CNTO   0         // int[50000]  out-degree
#define O_CNTI   50000     // int[50000]  in-degree (also bucket fill)
#define O_OVFN   100000    // int[1]      overflow count
#define O_OVF    100002    // int2[8192]  overflow (dst,src) pairs
#define O_BUCKET 120000    // int[50000*64] src per slot
#define O_HB     3320000   // uint[3.2M]  bf16x2 h*norm_out
#define O_AGGB   6520000   // uint[3.2M]  bf16x2 agg rows (256 B/node)
#define O_WT     9720000   // uint[24576] bf16 W^T for Q,K,V: [3][128 n][64 k-pairs]
#define O_QB     9750000   // uint[3.2M]  bf16x2 Q rows (64 uints/node)
#define O_KV     12950000  // uint[6.4M]  interleaved bf16 K/V rows (512 B/node)

typedef unsigned int uint;
typedef __attribute__((ext_vector_type(8))) short short8;
typedef __attribute__((ext_vector_type(4))) float floatx4;

union U16 { uint4 u; short8 s; };

__device__ __forceinline__ uint f2bf2(float a, float b) {
    uint ua = __float_as_uint(a); ua = (ua + 0x7fffu + ((ua >> 16) & 1u)) >> 16;
    uint ub = __float_as_uint(b); ub = (ub + 0x7fffu + ((ub >> 16) & 1u)) >> 16;
    return ua | (ub << 16);
}
__device__ __forceinline__ float bflo(uint u) { return __uint_as_float(u << 16); }
__device__ __forceinline__ float bfhi(uint u) { return __uint_as_float(u & 0xffff0000u); }

// One-pass build: out-degree histogram + dst-buckets (with overflow safety net).
__global__ __launch_bounds__(256) void k_build(const int* __restrict__ src,
                                               const int* __restrict__ dst,
                                               int* cnt_out, int* cnt_in,
                                               int* __restrict__ bucket,
                                               int* ovf_n, int2* __restrict__ ovf) {
    int e = blockIdx.x * 256 + threadIdx.x;
    if (e < N_EDGES) {
        int s = src[e], d = dst[e];
        atomicAdd(&cnt_out[s], 1);
        int pos = atomicAdd(&cnt_in[d], 1);
        if (pos < CAP) {
            bucket[(d << 6) + pos] = s;
        } else {
            int o = atomicAdd(ovf_n, 1);
            if (o < OVF_CAP) ovf[o] = make_int2(d, s);
        }
    }
}

// W^T cast: wt[y][n][k2] = bf16x2(W_y[2k2][n], W_y[2k2+1][n])
__global__ __launch_bounds__(256) void k_wt(const float* __restrict__ WQ,
                                            const float* __restrict__ WK,
                                            const float* __restrict__ WV,
                                            uint* __restrict__ wt) {
    int idx = blockIdx.x * 256 + threadIdx.x;   // [0, 3*8192)
    if (idx < 3 * 8192) {
        int y = idx >> 13;
        int rem = idx & 8191;
        int k2 = rem >> 7;          // 0..63
        int n  = rem & 127;         // coalesced reads
        const float* W = (y == 0) ? WQ : (y == 1) ? WK : WV;
        float a = W[(2 * k2) * 128 + n];
        float b = W[(2 * k2 + 1) * 128 + n];
        wt[(y << 13) + (n << 6) + k2] = f2bf2(a, b);
    }
}

// hb[n][j] = bf16(h[n][j] * rsqrt(max(deg_out,1)))
__global__ __launch_bounds__(256) void k_hb(const float* __restrict__ h,
                                            const int* __restrict__ cnt_out,
                                            uint* __restrict__ hb) {
    int idx = blockIdx.x * 256 + threadIdx.x;   // [0, N*64)
    if (idx < N_NODES * 64) {
        int n = idx >> 6;
        float no = rsqrtf(fmaxf((float)cnt_out[n], 1.0f));
        float2 hv = *(const float2*)(h + ((size_t)idx << 1));
        hb[idx] = f2bf2(hv.x * no, hv.y * no);
    }
}

// aggb[n] = bf16( rsqrt(max(deg_in,1)) * sum_{slots of n} hb[s] ); unroll x8
__global__ __launch_bounds__(256) void k_agg(
    const int* __restrict__ cnt_in, const int* __restrict__ bucket,
    const int* __restrict__ ovf_n, const int2* __restrict__ ovf,
    const uint* __restrict__ hb, uint* __restrict__ aggb)
{
    int n = blockIdx.x * 4 + (threadIdx.x >> 6);
    int lane = threadIdx.x & 63;
    int cnt = cnt_in[n];
    int m = min(cnt, CAP);
    const int* b = bucket + ((size_t)n << 6);
    float ax = 0.f, ay = 0.f;
    int i = 0;
    for (; i + 8 <= m; i += 8) {
        int s[8]; uint u[8];
        #pragma unroll
        for (int j = 0; j < 8; ++j) s[j] = b[i + j];
        #pragma unroll
        for (int j = 0; j < 8; ++j) u[j] = hb[((size_t)s[j] << 6) + lane];
        #pragma unroll
        for (int j = 0; j < 8; ++j) { ax += bflo(u[j]); ay += bfhi(u[j]); }
    }
    for (; i < m; ++i) {
        int s = b[i];
        uint u = hb[((size_t)s << 6) + lane];
        ax += bflo(u);
        ay += bfhi(u);
    }
    if (cnt > CAP) {                       // statistically never; correctness net
        int on = min(*ovf_n, OVF_CAP);
        for (int j = 0; j < on; ++j) {
            int2 p = ovf[j];
            if (p.x == n) {
                uint u = hb[((size_t)p.y << 6) + lane];
                ax += bflo(u);
                ay += bfhi(u);
            }
        }
    }
    float ni = rsqrtf(fmaxf((float)cnt, 1.0f));
    aggb[((size_t)n << 6) + lane] = f2bf2(ax * ni, ay * ni);
}

// Fused QKV projection via bf16 MFMA. grid (391, 3): y=0 -> qb (bf16 rows),
// y=1 -> K half of interleaved kv, y=2 -> V half.
__global__ __launch_bounds__(256) void k_qkv(
    const uint* __restrict__ aggb, const uint* __restrict__ wt,
    const float* __restrict__ bQ, const float* __restrict__ bK,
    const float* __restrict__ bV,
    uint* __restrict__ qb, uint* __restrict__ kv)
{
    const int y = blockIdx.y;
    const int row0 = blockIdx.x * 128;
    const float* bias = (y == 0) ? bQ : (y == 1) ? bK : bV;

    __shared__ uint sA[128 * 68];   // A tile, row stride 68 uints

    const int t = threadIdx.x;
    for (int idx = t; idx < 128 * 16; idx += 256) {
        int r = idx >> 4, c4 = (idx & 15) << 2;
        int row = row0 + r;
        uint4 v = make_uint4(0u, 0u, 0u, 0u);
        if (row < N_NODES) v = *(const uint4*)(aggb + ((size_t)row << 6) + c4);
        *(uint4*)(&sA[r * 68 + c4]) = v;
    }
    __syncthreads();

    const int wave = t >> 6;
    const int lane = t & 63;
    const int mrow = lane & 15;     // m (A) / n (B) / col (C)
    const int kq   = lane >> 4;     // 0..3
    const int mbase = wave * 32;
    const uint* wty = wt + (y << 13);

    floatx4 acc[2][8];
    for (int a = 0; a < 2; ++a)
        for (int b = 0; b < 8; ++b)
            acc[a][b] = (floatx4){0.f, 0.f, 0.f, 0.f};

    for (int kc = 0; kc < 128; kc += 32) {
        int koff = (kc >> 1) + (kq << 2);    // uint offset within a row
        short8 afr[2], bfr[8];
        for (int mt = 0; mt < 2; ++mt) {
            U16 u; u.u = *(const uint4*)(&sA[(mbase + mt * 16 + mrow) * 68 + koff]);
            afr[mt] = u.s;
        }
        for (int nt = 0; nt < 8; ++nt) {
            U16 u; u.u = *(const uint4*)(wty + ((nt * 16 + mrow) << 6) + koff);
            bfr[nt] = u.s;
        }
        for (int mt = 0; mt < 2; ++mt)
            for (int nt = 0; nt < 8; ++nt)
                acc[mt][nt] = __builtin_amdgcn_mfma_f32_16x16x32_bf16(
                    afr[mt], bfr[nt], acc[mt][nt], 0, 0, 0);
    }

    // C/D: col = lane&15 (= mrow), row = kq*4 + reg. Pack pairs via shfl_xor(1).
    if (y == 0) {
        for (int mt = 0; mt < 2; ++mt) {
            int rbase = row0 + mbase + mt * 16 + kq * 4;
            for (int nt = 0; nt < 8; ++nt) {
                int c = nt * 16 + mrow;
                float bv = bias[c];
                for (int r = 0; r < 4; ++r) {
                    float v = fmaxf(acc[mt][nt][r] + bv, 0.f);
                    float pv = __shfl_xor(v, 1);
                    int row = rbase + r;
                    if (((lane & 1) == 0) && row < N_NODES)
                        qb[((size_t)row << 6) + (c >> 1)] = f2bf2(v, pv);
                }
            }
        }
    } else {
        const int vo = (y == 2) ? 1 : 0;
        for (int mt = 0; mt < 2; ++mt) {
            int rbase = row0 + mbase + mt * 16 + kq * 4;
            for (int nt = 0; nt < 8; ++nt) {
                int c = nt * 16 + mrow;    // even for even lanes
                float bv = bias[c];
                for (int r = 0; r < 4; ++r) {
                    float v = fmaxf(acc[mt][nt][r] + bv, 0.f);
                    float pv = __shfl_xor(v, 1);
                    int row = rbase + r;
                    if (((lane & 1) == 0) && row < N_NODES)
                        kv[((size_t)row << 7) + c + vo] = f2bf2(v, pv);
                }
            }
        }
    }
}

__device__ __forceinline__ void attn_step(uint2 kvp, float qx, float qy,
                                          float& ax, float& ay, float& zacc) {
    float p = bflo(kvp.x) * qx + bfhi(kvp.x) * qy;
    p += __shfl_xor(p, 1);
    p += __shfl_xor(p, 2);
    p += __shfl_xor(p, 4);
    float sc = __expf(fminf(fmaxf(p * 0.25f, -10.f), 10.f));
    ax += bflo(kvp.y) * sc;
    ay += bfhi(kvp.y) * sc;
    zacc += sc;
}

// Attention gather over interleaved KV from buckets; one wave per node; unroll x8.
// lane owns dim pair `lane` (head = lane>>3).
__global__ __launch_bounds__(256) void k_attn(
    const int* __restrict__ cnt_in, const int* __restrict__ bucket,
    const int* __restrict__ ovf_n, const int2* __restrict__ ovf,
    const uint* __restrict__ qb, const uint* __restrict__ kv,
    float* __restrict__ out)
{
    int n = blockIdx.x * 4 + (threadIdx.x >> 6);
    int lane = threadIdx.x & 63;
    int cnt = cnt_in[n];
    int m = min(cnt, CAP);
    const int* b = bucket + ((size_t)n << 6);

    uint qu = qb[((size_t)n << 6) + lane];
    float qx = bflo(qu), qy = bfhi(qu);
    float ax = 0.f, ay = 0.f, zacc = 0.f;

    int i = 0;
    for (; i + 8 <= m; i += 8) {
        int s[8]; uint2 p[8];
        #pragma unroll
        for (int j = 0; j < 8; ++j) s[j] = b[i + j];
        #pragma unroll
        for (int j = 0; j < 8; ++j)
            p[j] = *(const uint2*)(kv + ((size_t)s[j] << 7) + (lane << 1));
        #pragma unroll
        for (int j = 0; j < 8; ++j)
            attn_step(p[j], qx, qy, ax, ay, zacc);
    }
    for (; i < m; ++i) {
        int s = b[i];
        uint2 p = *(const uint2*)(kv + ((size_t)s << 7) + (lane << 1));
        attn_step(p, qx, qy, ax, ay, zacc);
    }
    if (cnt > CAP) {                       // statistically never; correctness net
        int on = min(*ovf_n, OVF_CAP);
        for (int j = 0; j < on; ++j) {
            int2 pr = ovf[j];
            if (pr.x == n) {
                uint2 p = *(const uint2*)(kv + ((size_t)pr.y << 7) + (lane << 1));
                attn_step(p, qx, qy, ax, ay, zacc);
            }
        }
    }

    float inv = 1.0f / (zacc + 1e-6f);
    float2 o; o.x = ax * inv; o.y = ay * inv;
    *(float2*)(out + ((size_t)n << 7) + (lane << 1)) = o;
}

extern "C" void kernel_launch(void* const* d_in, const int* in_sizes, int n_in,
                              void* d_out, int out_size, void* d_ws, size_t ws_size,
                              hipStream_t stream) {
    const float* h   = (const float*)d_in[0];
    const float* WQ  = (const float*)d_in[1];
    const float* bQ  = (const float*)d_in[2];
    const float* WK  = (const float*)d_in[3];
    const float* bK  = (const float*)d_in[4];
    const float* WV  = (const float*)d_in[5];
    const float* bV  = (const float*)d_in[6];
    const int*   src = (const int*)d_in[7];
    const int*   dst = (const int*)d_in[8];
    float* out = (float*)d_out;
    float* ws  = (float*)d_ws;
    int*   wsi = (int*)d_ws;

    int*   cnt_out = wsi + O_CNTO;
    int*   cnt_in  = wsi + O_CNTI;
    int*   ovf_n   = wsi + O_OVFN;
    int2*  ovf     = (int2*)(wsi + O_OVF);
    int*   bucket  = wsi + O_BUCKET;
    uint*  hb      = (uint*)(ws + O_HB);
    uint*  aggb    = (uint*)(ws + O_AGGB);
    uint*  wt      = (uint*)(ws + O_WT);
    uint*  qb      = (uint*)(ws + O_QB);
    uint*  kv      = (uint*)(ws + O_KV);

    hipMemsetAsync(wsi, 0, (2 * N_NODES + 2) * sizeof(int), stream);

    k_wt<<<(3 * 8192 + 255) / 256, 256, 0, stream>>>(WQ, WK, WV, wt);
    k_build<<<N_EDGES / 256, 256, 0, stream>>>(src, dst, cnt_out, cnt_in,
                                               bucket, ovf_n, ovf);
    k_hb<<<(N_NODES * 64 + 255) / 256, 256, 0, stream>>>(h, cnt_out, hb);

    k_agg<<<N_NODES / 4, 256, 0, stream>>>(cnt_in, bucket, ovf_n, ovf, hb, aggb);

    dim3 g_qkv((N_NODES + 127) / 128, 3);
    k_qkv<<<g_qkv, 256, 0, stream>>>(aggb, wt, bQ, bK, bV, qb, kv);

    k_attn<<<N_NODES / 4, 256, 0, stream>>>(cnt_in, bucket, ovf_n, ovf,
                                            qb, kv, out);
}